// Round 9
// baseline (811.307 us; speedup 1.0000x reference)
//
#include <hip/hip_runtime.h>

#define NNODES 8192
#define KN 32
#define CC 16
#define HD 64

typedef unsigned short u16;

__device__ __forceinline__ float bf2f(u16 u) {
    union { unsigned int i; float f; } v; v.i = ((unsigned int)u) << 16; return v.f;
}
__device__ __forceinline__ u16 f2bf(float f) {
    union { float ff; unsigned int i; } v; v.ff = f;
    unsigned int r = v.i + 0x7FFFu + ((v.i >> 16) & 1u);
    return (u16)(r >> 16);
}
__device__ __forceinline__ float4 bf2f4(ushort4 u) {
    float4 r; r.x = bf2f(u.x); r.y = bf2f(u.y); r.z = bf2f(u.z); r.w = bf2f(u.w); return r;
}
__device__ __forceinline__ float silu_f(float x) { return x / (1.0f + __expf(-x)); }

template<bool F32>
__device__ __forceinline__ float ldf(const void* p, int i) {
    if constexpr (F32) return ((const float*)p)[i];
    else               return bf2f(((const u16*)p)[i]);
}
template<bool F32>
__device__ __forceinline__ float4 ldx4(const void* p, int i) {  // elements i..i+3, i%4==0
    if constexpr (F32) return ((const float4*)p)[i >> 2];
    else               return bf2f4(((const ushort4*)p)[i >> 2]);
}
template<bool F32>
__device__ __forceinline__ void stf(void* p, int i, float v) {
    if constexpr (F32) ((float*)p)[i] = v;
    else               ((u16*)p)[i] = f2bf(v);
}

__device__ __forceinline__ void fma4(float4& a, const float4 rv,
                                     const float4 w0, const float4 w1,
                                     const float4 w2, const float4 w3) {
    a.x += rv.x*w0.x + rv.y*w1.x + rv.z*w2.x + rv.w*w3.x;
    a.y += rv.x*w0.y + rv.y*w1.y + rv.z*w2.y + rv.w*w3.y;
    a.z += rv.x*w0.z + rv.y*w1.z + rv.z*w2.z + rv.w*w3.z;
    a.w += rv.x*w0.w + rv.y*w1.w + rv.z*w2.w + rv.w*w3.w;
}

// IDENTICAL layout to the proven 696us r5 kernel: 53760 B -> 3 blocks/CU.
// (fp16 LDS compression is numerically DEAD for this op: type_norm's
//  1/sqrt(var) amplifies accumulator storage noise ~100x at var-degenerate
//  nodes — r7/r8 failed at absmax ~2-3. fp32 everywhere.)
struct __align__(16) Smem {
    union {
        float W2s[HD * HD];                                  // 16384 B, live stage->C
        struct { float G[3][16][68]; float red[4][16][3]; } g;  // live D->F (13824 B)
    } u;
    float rbf[KN][16];       // 2048
    float e[KN][4];          // 512
    float f0n[KN][CC];       // 2048
    float f1n[KN][CC][3];    // 6144
    float con[KN][CC][4];    // 8192  (fp32! d padded to 4)
    float h1[KN][68];        // 8704  (row padded 64->68)
    float h2[KN][68];        // 8704
    float S[3][CC];          // 192
    float out0[CC];
    float out1[CC][3];
    float f0self[CC];
    float f1self[CC][3];
    float f0g[CC];
    float fac1[CC];
};

template<bool F32, bool I64>
__device__ void gttfn_body(Smem& sm,
                           const void* f0,  const void* f1,
                           const void* rbf, const void* gte,
                           const void* W1,  const void* b1,
                           const void* W2,  const void* b2,
                           const void* W3,  const void* b3,
                           const void* lg0, const void* lb0,
                           const void* lg1, const void* lb1,
                           const void* gW0, const void* gb0,
                           const void* gW1, const void* gb1,
                           const void* rW0, const void* rW1,
                           const int* __restrict__ nbr,
                           void* out)
{
    const int tid  = threadIdx.x;
    const int n    = blockIdx.x;
    const int lane = tid & 63;
    const int wv   = tid >> 6;

    // ---- preamble (proven) ----
    for (int i = tid; i < KN * 16; i += 256)
        ((float*)sm.rbf)[i] = ldf<F32>(rbf, n * KN * 16 + i);
    if (tid < KN * 4)
        ((float*)sm.e)[tid] = ldf<F32>(gte, n * KN * 4 + tid);
    for (int idx = tid; idx < KN * CC; idx += 256) {
        int j = idx >> 4, c = idx & 15;
        int nb = I64 ? nbr[2 * (n * KN + j)] : nbr[n * KN + j];
        sm.f0n[j][c] = ldf<F32>(f0, nb * CC + c);
        int base = (nb * CC + c) * 3;
        sm.f1n[j][c][0] = ldf<F32>(f1, base + 0);
        sm.f1n[j][c][1] = ldf<F32>(f1, base + 1);
        sm.f1n[j][c][2] = ldf<F32>(f1, base + 2);
    }
    if (tid < CC) { sm.f0self[tid] = ldf<F32>(f0, n * CC + tid); sm.out0[tid] = 0.f; }
    else if (tid < CC + 48) {
        int k = tid - CC;
        ((float*)sm.f1self)[k] = ldf<F32>(f1, n * CC * 3 + k);
        ((float*)sm.out1)[k] = 0.f;
    }
    __syncthreads();

    const int dot_arr[5] = {1, 3, 3, 1, 3};
    const int ot_arr[5]  = {0, 1, 1, 0, 1};

    for (int t = 0; t < 5; ++t) {
        const int dt = dot_arr[t];

        // ---- phase A: con fp32 (keeps D's hot loop branch-free) ----
        for (int idx = tid; idx < KN * CC; idx += 256) {
            int j = idx >> 4, c = idx & 15;
            float e0v = sm.e[j][0];
            float ex = sm.e[j][1], ey = sm.e[j][2], ez = sm.e[j][3];
            if (t == 0) {
                sm.con[j][c][0] = e0v * sm.f0n[j][c];
            } else if (t == 1) {
                float fv = sm.f0n[j][c];
                sm.con[j][c][0] = ex * fv; sm.con[j][c][1] = ey * fv; sm.con[j][c][2] = ez * fv;
            } else if (t == 2) {
                sm.con[j][c][0] = e0v * sm.f1n[j][c][0];
                sm.con[j][c][1] = e0v * sm.f1n[j][c][1];
                sm.con[j][c][2] = e0v * sm.f1n[j][c][2];
            } else if (t == 3) {
                sm.con[j][c][0] = ex * sm.f1n[j][c][0] + ey * sm.f1n[j][c][1]
                                + ez * sm.f1n[j][c][2];
            } else {
                float fx = sm.f1n[j][c][0], fy = sm.f1n[j][c][1], fz = sm.f1n[j][c][2];
                sm.con[j][c][0] = fy * ez - fz * ey;
                sm.con[j][c][1] = fz * ex - fx * ez;
                sm.con[j][c][2] = fx * ey - fy * ex;
            }
        }

        // ---- stage W2[t] -> LDS fp32 (32x reuse in phase C) ----
        for (int i = tid; i < 1024; i += 256) {
            float4 w = ldx4<F32>(W2, t * 4096 + i * 4);
            *(float4*)&sm.u.W2s[i * 4] = w;
        }

        // ---- phase B: h1 = silu(rbf @ W1 + b1), fp32 ----
        for (int task = tid; task < KN * 16; task += 256) {
            int j = task >> 4, hq = task & 15;
            float4 acc = ldx4<F32>(b1, t * 64 + hq * 4);
            const float4* rrow = (const float4*)(&sm.rbf[j][0]);
#pragma unroll
            for (int r4 = 0; r4 < 4; ++r4) {
                float4 rv = rrow[r4];
                float4 w0 = ldx4<F32>(W1, t * 1024 + (r4 * 4 + 0) * 64 + hq * 4);
                float4 w1 = ldx4<F32>(W1, t * 1024 + (r4 * 4 + 1) * 64 + hq * 4);
                float4 w2 = ldx4<F32>(W1, t * 1024 + (r4 * 4 + 2) * 64 + hq * 4);
                float4 w3 = ldx4<F32>(W1, t * 1024 + (r4 * 4 + 3) * 64 + hq * 4);
                acc.x += rv.x * w0.x + rv.y * w1.x + rv.z * w2.x + rv.w * w3.x;
                acc.y += rv.x * w0.y + rv.y * w1.y + rv.z * w2.y + rv.w * w3.y;
                acc.z += rv.x * w0.z + rv.y * w1.z + rv.z * w2.z + rv.w * w3.z;
                acc.w += rv.x * w0.w + rv.y * w1.w + rv.z * w2.w + rv.w * w3.w;
            }
            float4 r;
            r.x = silu_f(acc.x); r.y = silu_f(acc.y);
            r.z = silu_f(acc.z); r.w = silu_f(acc.w);
            *(float4*)&sm.h1[j][hq * 4] = r;
        }
        __syncthreads();

        // ---- phase C: h2 = silu(h1 @ W2s + b2) -- j-QUAD (vs r5's j-pair):
        // 128 active threads, 4 rows each share the 4 W2s register loads.
        // LDS wave-instructions per block-t: 384 -> 256 (-33%). ----
        if (tid < 128) {
            const int jp = tid >> 4, hq = tid & 15;   // jp 0..7
            const int j0 = jp, j1 = jp + 8, j2 = jp + 16, j3 = jp + 24;
            float4 b = ldx4<F32>(b2, t * 64 + hq * 4);
            float4 a0 = b, a1 = b, a2 = b, a3 = b;
#pragma unroll 4
            for (int h4 = 0; h4 < 16; ++h4) {
                const float* Wr = &sm.u.W2s[(h4 * 4) * 64 + hq * 4];
                float4 w0 = *(const float4*)(Wr);
                float4 w1 = *(const float4*)(Wr + 64);
                float4 w2 = *(const float4*)(Wr + 128);
                float4 w3 = *(const float4*)(Wr + 192);
                float4 hv0 = *(const float4*)&sm.h1[j0][h4 * 4];
                float4 hv1 = *(const float4*)&sm.h1[j1][h4 * 4];
                float4 hv2 = *(const float4*)&sm.h1[j2][h4 * 4];
                float4 hv3 = *(const float4*)&sm.h1[j3][h4 * 4];
                fma4(a0, hv0, w0, w1, w2, w3);
                fma4(a1, hv1, w0, w1, w2, w3);
                fma4(a2, hv2, w0, w1, w2, w3);
                fma4(a3, hv3, w0, w1, w2, w3);
            }
            float4 r0, r1, r2, r3;
            r0.x = silu_f(a0.x); r0.y = silu_f(a0.y); r0.z = silu_f(a0.z); r0.w = silu_f(a0.w);
            r1.x = silu_f(a1.x); r1.y = silu_f(a1.y); r1.z = silu_f(a1.z); r1.w = silu_f(a1.w);
            r2.x = silu_f(a2.x); r2.y = silu_f(a2.y); r2.z = silu_f(a2.z); r2.w = silu_f(a2.w);
            r3.x = silu_f(a3.x); r3.y = silu_f(a3.y); r3.z = silu_f(a3.z); r3.w = silu_f(a3.w);
            *(float4*)&sm.h2[j0][hq * 4] = r0;
            *(float4*)&sm.h2[j1][hq * 4] = r1;
            *(float4*)&sm.h2[j2][hq * 4] = r2;
            *(float4*)&sm.h2[j3][hq * 4] = r3;
        }
        __syncthreads();

        // ---- phase D: G[d][c][h] + S -- c-PAIR (c, c+8): 128 active threads,
        // the h2 quad read is shared across both channels.
        // LDS wave-instructions per block-t: 256 -> 192 (-25%). ----
        if (tid < 128) {
            int hq = tid & 15, c2 = tid >> 4;        // c2 0..7
            const int ca = c2, cb = c2 + 8;
            float4 g0a = make_float4(0, 0, 0, 0), g1a = g0a, g2a = g0a;
            float4 g0b = g0a, g1b = g0a, g2b = g0a;
            float sxa = 0, sya = 0, sza = 0, sxb = 0, syb = 0, szb = 0;
            if (dt == 1) {
#pragma unroll 4
                for (int j = 0; j < KN; ++j) {
                    float4 h2q = *(const float4*)&sm.h2[j][hq * 4];
                    float cva = sm.con[j][ca][0];
                    float cvb = sm.con[j][cb][0];
                    g0a.x += h2q.x * cva; g0a.y += h2q.y * cva;
                    g0a.z += h2q.z * cva; g0a.w += h2q.w * cva;
                    g0b.x += h2q.x * cvb; g0b.y += h2q.y * cvb;
                    g0b.z += h2q.z * cvb; g0b.w += h2q.w * cvb;
                    sxa += cva; sxb += cvb;
                }
            } else {
#pragma unroll 4
                for (int j = 0; j < KN; ++j) {
                    float4 h2q = *(const float4*)&sm.h2[j][hq * 4];
                    float4 cva = *(const float4*)&sm.con[j][ca][0];
                    float4 cvb = *(const float4*)&sm.con[j][cb][0];
                    g0a.x += h2q.x * cva.x; g0a.y += h2q.y * cva.x; g0a.z += h2q.z * cva.x; g0a.w += h2q.w * cva.x;
                    g1a.x += h2q.x * cva.y; g1a.y += h2q.y * cva.y; g1a.z += h2q.z * cva.y; g1a.w += h2q.w * cva.y;
                    g2a.x += h2q.x * cva.z; g2a.y += h2q.y * cva.z; g2a.z += h2q.z * cva.z; g2a.w += h2q.w * cva.z;
                    g0b.x += h2q.x * cvb.x; g0b.y += h2q.y * cvb.x; g0b.z += h2q.z * cvb.x; g0b.w += h2q.w * cvb.x;
                    g1b.x += h2q.x * cvb.y; g1b.y += h2q.y * cvb.y; g1b.z += h2q.z * cvb.y; g1b.w += h2q.w * cvb.y;
                    g2b.x += h2q.x * cvb.z; g2b.y += h2q.y * cvb.z; g2b.z += h2q.z * cvb.z; g2b.w += h2q.w * cvb.z;
                    sxa += cva.x; sya += cva.y; sza += cva.z;
                    sxb += cvb.x; syb += cvb.y; szb += cvb.z;
                }
            }
            *(float4*)&sm.u.g.G[0][ca][hq * 4] = g0a;
            *(float4*)&sm.u.g.G[0][cb][hq * 4] = g0b;
            if (dt == 3) {
                *(float4*)&sm.u.g.G[1][ca][hq * 4] = g1a;
                *(float4*)&sm.u.g.G[2][ca][hq * 4] = g2a;
                *(float4*)&sm.u.g.G[1][cb][hq * 4] = g1b;
                *(float4*)&sm.u.g.G[2][cb][hq * 4] = g2b;
            }
            if (hq == 0) {
                sm.S[0][ca] = sxa; sm.S[0][cb] = sxb;
                if (dt == 3) {
                    sm.S[1][ca] = sya; sm.S[2][ca] = sza;
                    sm.S[1][cb] = syb; sm.S[2][cb] = szb;
                }
            }
        }
        __syncthreads();

        // ---- phase E: vectorized W3, in-wave shuffle reduce over h (proven) ----
        {
            const int h = tid >> 2, o4 = tid & 3;
            float acc[3][4] = {{0,0,0,0},{0,0,0,0},{0,0,0,0}};
#pragma unroll 4
            for (int c = 0; c < 16; ++c) {
                float4 wq = ldx4<F32>(W3, t * 16384 + h * 256 + c * 16 + o4 * 4);
                float g0v = sm.u.g.G[0][c][h];
                acc[0][0] += g0v * wq.x; acc[0][1] += g0v * wq.y;
                acc[0][2] += g0v * wq.z; acc[0][3] += g0v * wq.w;
                if (dt == 3) {
                    float g1v = sm.u.g.G[1][c][h];
                    float g2v = sm.u.g.G[2][c][h];
                    acc[1][0] += g1v * wq.x; acc[1][1] += g1v * wq.y;
                    acc[1][2] += g1v * wq.z; acc[1][3] += g1v * wq.w;
                    acc[2][0] += g2v * wq.x; acc[2][1] += g2v * wq.y;
                    acc[2][2] += g2v * wq.z; acc[2][3] += g2v * wq.w;
                }
            }
            // reduce over the wave's 16 h values (lane bits 2..5)
#pragma unroll
            for (int m = 4; m <= 32; m <<= 1) {
#pragma unroll
                for (int d = 0; d < 3; ++d) {
                    if (d < dt) {
#pragma unroll
                        for (int oo = 0; oo < 4; ++oo)
                            acc[d][oo] += __shfl_xor(acc[d][oo], m);
                    }
                }
            }
            if (lane < 4) {
#pragma unroll
                for (int d = 0; d < 3; ++d) {
                    if (d < dt) {
#pragma unroll
                        for (int oo = 0; oo < 4; ++oo)
                            sm.u.g.red[wv][lane * 4 + oo][d] = acc[d][oo];
                    }
                }
            }
        }
        __syncthreads();

        // ---- phase F: combine wave partials + b3*S (proven) ----
        if (tid < 16 * dt) {
            int o = tid & 15, d = tid >> 4;
            float s = sm.u.g.red[0][o][d] + sm.u.g.red[1][o][d]
                    + sm.u.g.red[2][o][d] + sm.u.g.red[3][o][d];
#pragma unroll 4
            for (int c = 0; c < 16; ++c)
                s += ldf<F32>(b3, t * 256 + c * 16 + o) * sm.S[d][c];
            if (ot_arr[t] == 0) sm.out0[o] += s;
            else                sm.out1[o][d] += s;
        }
        __syncthreads();
    }

    // ---- epilogue (proven) ----
    if (tid < 32) {
        if (tid < 16) {
            int c = tid;
            float v = sm.out0[c];
            float nrm = fmaxf(fabsf(v), 1e-8f);
            float mu = nrm;
#pragma unroll
            for (int m = 8; m >= 1; m >>= 1) mu += __shfl_xor(mu, m, 16);
            mu *= (1.0f / 16.0f);
            float dl = nrm - mu;
            float var = dl * dl;
#pragma unroll
            for (int m = 8; m >= 1; m >>= 1) var += __shfl_xor(var, m, 16);
            var *= (1.0f / 16.0f);
            float scaled = dl / sqrtf(var + 1e-5f) * ldf<F32>(lg0, c) + ldf<F32>(lb0, c);
            sm.f0g[c] = v / nrm * scaled;
        } else {
            int c = tid - 16;
            float x = sm.out1[c][0], y = sm.out1[c][1], z = sm.out1[c][2];
            float nrm = fmaxf(sqrtf(x * x + y * y + z * z), 1e-8f);
            float mu = nrm;
#pragma unroll
            for (int m = 8; m >= 1; m >>= 1) mu += __shfl_xor(mu, m, 16);
            mu *= (1.0f / 16.0f);
            float dl = nrm - mu;
            float var = dl * dl;
#pragma unroll
            for (int m = 8; m >= 1; m >>= 1) var += __shfl_xor(var, m, 16);
            var *= (1.0f / 16.0f);
            float scaled = dl / sqrtf(var + 1e-5f) * ldf<F32>(lg1, c) + ldf<F32>(lb1, c);
            sm.fac1[c] = scaled / nrm;
        }
    }
    __syncthreads();
    if (tid < 16) {
        int o = tid;
        float a0 = ldf<F32>(gb0, o), a1 = ldf<F32>(gb1, o);
        float r0 = 0, rx = 0, ry = 0, rz = 0;
#pragma unroll 4
        for (int c = 0; c < 16; ++c) {
            float fg = sm.f0g[c];
            a0 += fg * ldf<F32>(gW0, c * 16 + o);
            a1 += fg * ldf<F32>(gW1, c * 16 + o);
            r0 += sm.f0self[c] * ldf<F32>(rW0, c * 16 + o);
            float rw1 = ldf<F32>(rW1, c * 16 + o);
            rx += sm.f1self[c][0] * rw1; ry += sm.f1self[c][1] * rw1; rz += sm.f1self[c][2] * rw1;
        }
        float g0v = 1.f / (1.f + __expf(-a0));
        float g1v = 1.f / (1.f + __expf(-a1));
        stf<F32>(out, n * 16 + o, sm.f0g[o] * g0v + r0);
        int b = NNODES * CC + (n * 16 + o) * 3;
        float fac = sm.fac1[o] * g1v;
        stf<F32>(out, b + 0, sm.out1[o][0] * fac + rx);
        stf<F32>(out, b + 1, sm.out1[o][1] * fac + ry);
        stf<F32>(out, b + 2, sm.out1[o][2] * fac + rz);
    }
}

__global__ __launch_bounds__(256)
void gttfn_kernel(const void* f0,  const void* f1,
                  const void* rbf, const void* gte,
                  const void* W1,  const void* b1,
                  const void* W2,  const void* b2,
                  const void* W3,  const void* b3,
                  const void* lg0, const void* lb0,
                  const void* lg1, const void* lb1,
                  const void* gW0, const void* gb0,
                  const void* gW1, const void* gb1,
                  const void* rW0, const void* rW1,
                  const void* nbr_v,
                  void* out)
{
    __shared__ Smem sm;
    __shared__ int flags[2];
    const int tid = threadIdx.x;

    if (tid < 64) {
        const u16* u = (const u16*)f0;
        unsigned short w = u[2 * tid];
        int e = (w >> 7) & 0xFF;
        bool garbage = (e >= 0x83) || (e <= 0x30);
        bool isF32 = __any(garbage);
        const int* ni = (const int*)nbr_v;
        bool hi_nonzero = (tid < 32) ? (ni[2 * tid + 1] != 0) : false;
        bool isI64 = !__any(hi_nonzero);
        if (tid == 0) { flags[0] = isF32 ? 1 : 0; flags[1] = isI64 ? 1 : 0; }
    }
    __syncthreads();
    int fF32 = flags[0], fI64 = flags[1];

    const int* nbr = (const int*)nbr_v;
    if (fF32) {
        if (fI64) gttfn_body<true, true >(sm, f0,f1,rbf,gte,W1,b1,W2,b2,W3,b3,lg0,lb0,lg1,lb1,gW0,gb0,gW1,gb1,rW0,rW1,nbr,out);
        else      gttfn_body<true, false>(sm, f0,f1,rbf,gte,W1,b1,W2,b2,W3,b3,lg0,lb0,lg1,lb1,gW0,gb0,gW1,gb1,rW0,rW1,nbr,out);
    } else {
        if (fI64) gttfn_body<false, true >(sm, f0,f1,rbf,gte,W1,b1,W2,b2,W3,b3,lg0,lb0,lg1,lb1,gW0,gb0,gW1,gb1,rW0,rW1,nbr,out);
        else      gttfn_body<false, false>(sm, f0,f1,rbf,gte,W1,b1,W2,b2,W3,b3,lg0,lb0,lg1,lb1,gW0,gb0,gW1,gb1,rW0,rW1,nbr,out);
    }
}

extern "C" void kernel_launch(void* const* d_in, const int* in_sizes, int n_in,
                              void* d_out, int out_size, void* d_ws, size_t ws_size,
                              hipStream_t stream) {
    gttfn_kernel<<<dim3(NNODES), dim3(256), 0, stream>>>(
        d_in[0],  d_in[1],  d_in[2],  d_in[3],
        d_in[4],  d_in[5],  d_in[6],  d_in[7],
        d_in[8],  d_in[9],  d_in[10], d_in[11],
        d_in[12], d_in[13], d_in[14], d_in[15],
        d_in[16], d_in[17], d_in[18], d_in[19],
        d_in[20], d_out);
}

// Round 10
// 683.553 us; speedup vs baseline: 1.1869x; 1.1869x over previous
//
#include <hip/hip_runtime.h>

#define NNODES 8192
#define KN 32
#define CC 16
#define HD 64

typedef unsigned short u16;

__device__ __forceinline__ float bf2f(u16 u) {
    union { unsigned int i; float f; } v; v.i = ((unsigned int)u) << 16; return v.f;
}
__device__ __forceinline__ u16 f2bf(float f) {
    union { float ff; unsigned int i; } v; v.ff = f;
    unsigned int r = v.i + 0x7FFFu + ((v.i >> 16) & 1u);
    return (u16)(r >> 16);
}
__device__ __forceinline__ float4 bf2f4(ushort4 u) {
    float4 r; r.x = bf2f(u.x); r.y = bf2f(u.y); r.z = bf2f(u.z); r.w = bf2f(u.w); return r;
}
__device__ __forceinline__ float silu_f(float x) { return x / (1.0f + __expf(-x)); }

template<bool F32>
__device__ __forceinline__ float ldf(const void* p, int i) {
    if constexpr (F32) return ((const float*)p)[i];
    else               return bf2f(((const u16*)p)[i]);
}
template<bool F32>
__device__ __forceinline__ float4 ldx4(const void* p, int i) {  // elements i..i+3, i%4==0
    if constexpr (F32) return ((const float4*)p)[i >> 2];
    else               return bf2f4(((const ushort4*)p)[i >> 2]);
}
template<bool F32>
__device__ __forceinline__ void stf(void* p, int i, float v) {
    if constexpr (F32) ((float*)p)[i] = v;
    else               ((u16*)p)[i] = f2bf(v);
}

__device__ __forceinline__ void fma4(float4& a, const float4 rv,
                                     const float4 w0, const float4 w1,
                                     const float4 w2, const float4 w3) {
    a.x += rv.x*w0.x + rv.y*w1.x + rv.z*w2.x + rv.w*w3.x;
    a.y += rv.x*w0.y + rv.y*w1.y + rv.z*w2.y + rv.w*w3.y;
    a.z += rv.x*w0.z + rv.y*w1.z + rv.z*w2.z + rv.w*w3.z;
    a.w += rv.x*w0.w + rv.y*w1.w + rv.z*w2.w + rv.w*w3.w;
}

// 53760 B -> 3 blocks/CU, identical footprint to the proven 696us r5 kernel.
// LDS-pipe model: ~51K cy/block x 32 blocks/CU ~= 681us ~= measured 696
// => LDS pipe ~98% busy is THE wall. All changes below only remove LDS
// instructions while keeping every phase 256-thread (r9 lesson: idling
// half the waves costs more than the instructions saved).
// red2 overlays con: con live A->D, red2 live E->F, barrier-separated.
struct __align__(16) Smem {
    union {
        float W2s[HD * HD];                      // 16384 B, live stage->C
        struct { float G[3][16][68]; } g;        // 13056 B, live D->E
    } u;
    union {
        float con[KN][CC][4];                    // 8192 B, live A->D
        float red2[4][4][16][3];                 // 3072 B, live E->F [wave][hql][o][d]
    } v;
    float rbf[KN][16];       // 2048
    float e[KN][4];          // 512
    float f0n[KN][CC];       // 2048
    float f1n[KN][CC][3];    // 6144
    float h1[KN][68];        // 8704  (row padded 64->68)
    float h2[KN][68];        // 8704
    float S[3][CC];          // 192
    float out0[CC];
    float out1[CC][3];
    float f0self[CC];
    float f1self[CC][3];
    float f0g[CC];
    float fac1[CC];
};

template<bool F32, bool I64>
__device__ void gttfn_body(Smem& sm,
                           const void* f0,  const void* f1,
                           const void* rbf, const void* gte,
                           const void* W1,  const void* b1,
                           const void* W2,  const void* b2,
                           const void* W3,  const void* b3,
                           const void* lg0, const void* lb0,
                           const void* lg1, const void* lb1,
                           const void* gW0, const void* gb0,
                           const void* gW1, const void* gb1,
                           const void* rW0, const void* rW1,
                           const int* __restrict__ nbr,
                           void* out)
{
    const int tid  = threadIdx.x;
    const int n    = blockIdx.x;
    const int lane = tid & 63;
    const int wv   = tid >> 6;

    // ---- preamble (proven) ----
    for (int i = tid; i < KN * 16; i += 256)
        ((float*)sm.rbf)[i] = ldf<F32>(rbf, n * KN * 16 + i);
    if (tid < KN * 4)
        ((float*)sm.e)[tid] = ldf<F32>(gte, n * KN * 4 + tid);
    for (int idx = tid; idx < KN * CC; idx += 256) {
        int j = idx >> 4, c = idx & 15;
        int nb = I64 ? nbr[2 * (n * KN + j)] : nbr[n * KN + j];
        sm.f0n[j][c] = ldf<F32>(f0, nb * CC + c);
        int base = (nb * CC + c) * 3;
        sm.f1n[j][c][0] = ldf<F32>(f1, base + 0);
        sm.f1n[j][c][1] = ldf<F32>(f1, base + 1);
        sm.f1n[j][c][2] = ldf<F32>(f1, base + 2);
    }
    if (tid < CC) { sm.f0self[tid] = ldf<F32>(f0, n * CC + tid); sm.out0[tid] = 0.f; }
    else if (tid < CC + 48) {
        int k = tid - CC;
        ((float*)sm.f1self)[k] = ldf<F32>(f1, n * CC * 3 + k);
        ((float*)sm.out1)[k] = 0.f;
    }
    __syncthreads();

    const int dot_arr[5] = {1, 3, 3, 1, 3};
    const int ot_arr[5]  = {0, 1, 1, 0, 1};

    for (int t = 0; t < 5; ++t) {
        const int dt = dot_arr[t];

        // ---- phase A: con fp32, float4 e-read + ONE float4 con-write ----
        for (int idx = tid; idx < KN * CC; idx += 256) {
            int j = idx >> 4, c = idx & 15;
            float4 ev = *(const float4*)&sm.e[j][0];   // e0, ex, ey, ez
            float4 cv; cv.y = 0.f; cv.z = 0.f; cv.w = 0.f;
            if (t == 0) {
                cv.x = ev.x * sm.f0n[j][c];
            } else if (t == 1) {
                float fv = sm.f0n[j][c];
                cv.x = ev.y * fv; cv.y = ev.z * fv; cv.z = ev.w * fv;
            } else if (t == 2) {
                cv.x = ev.x * sm.f1n[j][c][0];
                cv.y = ev.x * sm.f1n[j][c][1];
                cv.z = ev.x * sm.f1n[j][c][2];
            } else if (t == 3) {
                cv.x = ev.y * sm.f1n[j][c][0] + ev.z * sm.f1n[j][c][1]
                     + ev.w * sm.f1n[j][c][2];
            } else {
                float fx = sm.f1n[j][c][0], fy = sm.f1n[j][c][1], fz = sm.f1n[j][c][2];
                cv.x = fy * ev.w - fz * ev.z;
                cv.y = fz * ev.y - fx * ev.w;
                cv.z = fx * ev.z - fy * ev.y;
            }
            *(float4*)&sm.v.con[j][c][0] = cv;
        }

        // ---- stage W2[t] -> LDS fp32 (32x reuse in phase C) ----
        for (int i = tid; i < 1024; i += 256) {
            float4 w = ldx4<F32>(W2, t * 4096 + i * 4);
            *(float4*)&sm.u.W2s[i * 4] = w;
        }

        // ---- phase B: h1 = silu(rbf @ W1 + b1), fp32 (proven) ----
        for (int task = tid; task < KN * 16; task += 256) {
            int j = task >> 4, hq = task & 15;
            float4 acc = ldx4<F32>(b1, t * 64 + hq * 4);
            const float4* rrow = (const float4*)(&sm.rbf[j][0]);
#pragma unroll
            for (int r4 = 0; r4 < 4; ++r4) {
                float4 rv = rrow[r4];
                float4 w0 = ldx4<F32>(W1, t * 1024 + (r4 * 4 + 0) * 64 + hq * 4);
                float4 w1 = ldx4<F32>(W1, t * 1024 + (r4 * 4 + 1) * 64 + hq * 4);
                float4 w2 = ldx4<F32>(W1, t * 1024 + (r4 * 4 + 2) * 64 + hq * 4);
                float4 w3 = ldx4<F32>(W1, t * 1024 + (r4 * 4 + 3) * 64 + hq * 4);
                acc.x += rv.x * w0.x + rv.y * w1.x + rv.z * w2.x + rv.w * w3.x;
                acc.y += rv.x * w0.y + rv.y * w1.y + rv.z * w2.y + rv.w * w3.y;
                acc.z += rv.x * w0.z + rv.y * w1.z + rv.z * w2.z + rv.w * w3.z;
                acc.w += rv.x * w0.w + rv.y * w1.w + rv.z * w2.w + rv.w * w3.w;
            }
            float4 r;
            r.x = silu_f(acc.x); r.y = silu_f(acc.y);
            r.z = silu_f(acc.z); r.w = silu_f(acc.w);
            *(float4*)&sm.h1[j][hq * 4] = r;
        }
        __syncthreads();

        // ---- phase C: h2 = silu(h1 @ W2s + b2), j-pair (proven, 256 thr) ----
        {
            const int jp = tid >> 4, hq = tid & 15;
            const int j0 = jp, j1 = jp + 16;
            float4 a0 = ldx4<F32>(b2, t * 64 + hq * 4), a1 = a0;
#pragma unroll 4
            for (int h4 = 0; h4 < 16; ++h4) {
                const float* Wr = &sm.u.W2s[(h4 * 4) * 64 + hq * 4];
                float4 w0 = *(const float4*)(Wr);
                float4 w1 = *(const float4*)(Wr + 64);
                float4 w2 = *(const float4*)(Wr + 128);
                float4 w3 = *(const float4*)(Wr + 192);
                float4 hv0 = *(const float4*)&sm.h1[j0][h4 * 4];
                float4 hv1 = *(const float4*)&sm.h1[j1][h4 * 4];
                fma4(a0, hv0, w0, w1, w2, w3);
                fma4(a1, hv1, w0, w1, w2, w3);
            }
            float4 r0, r1;
            r0.x = silu_f(a0.x); r0.y = silu_f(a0.y);
            r0.z = silu_f(a0.z); r0.w = silu_f(a0.w);
            r1.x = silu_f(a1.x); r1.y = silu_f(a1.y);
            r1.z = silu_f(a1.z); r1.w = silu_f(a1.w);
            *(float4*)&sm.h2[j0][hq * 4] = r0;
            *(float4*)&sm.h2[j1][hq * 4] = r1;
        }
        __syncthreads();

        // ---- phase D: G[d][c][h] + S, branch-free hot loop (proven, 256 thr) ----
        {
            int hq = tid & 15, c = tid >> 4;
            float4 g0 = make_float4(0, 0, 0, 0), g1 = g0, g2 = g0;
            float sx = 0, sy = 0, sz = 0;
            if (dt == 1) {
#pragma unroll 4
                for (int j = 0; j < KN; ++j) {
                    float4 h2q = *(const float4*)&sm.h2[j][hq * 4];
                    float cv = sm.v.con[j][c][0];
                    g0.x += h2q.x * cv; g0.y += h2q.y * cv;
                    g0.z += h2q.z * cv; g0.w += h2q.w * cv;
                    sx += cv;
                }
            } else {
#pragma unroll 4
                for (int j = 0; j < KN; ++j) {
                    float4 h2q = *(const float4*)&sm.h2[j][hq * 4];
                    float4 cv = *(const float4*)&sm.v.con[j][c][0];
                    g0.x += h2q.x * cv.x; g0.y += h2q.y * cv.x; g0.z += h2q.z * cv.x; g0.w += h2q.w * cv.x;
                    g1.x += h2q.x * cv.y; g1.y += h2q.y * cv.y; g1.z += h2q.z * cv.y; g1.w += h2q.w * cv.y;
                    g2.x += h2q.x * cv.z; g2.y += h2q.y * cv.z; g2.z += h2q.z * cv.z; g2.w += h2q.w * cv.z;
                    sx += cv.x; sy += cv.y; sz += cv.z;
                }
            }
            *(float4*)&sm.u.g.G[0][c][hq * 4] = g0;
            if (dt == 3) {
                *(float4*)&sm.u.g.G[1][c][hq * 4] = g1;
                *(float4*)&sm.u.g.G[2][c][hq * 4] = g2;
            }
            if (hq == 0) {
                sm.S[0][c] = sx;
                if (dt == 3) { sm.S[1][c] = sy; sm.S[2][c] = sz; }
            }
        }
        __syncthreads();

        // ---- phase E: G @ W3; 2-step shuffle (h-quad sums) -> red2 ----
        // (halves the bpermute count vs r5's 4-step full-wave reduce;
        //  red2 lives in con's dead region, F sums 16 partials)
        {
            const int h = tid >> 2, o4 = tid & 3;
            float acc[3][4] = {{0,0,0,0},{0,0,0,0},{0,0,0,0}};
#pragma unroll 4
            for (int c = 0; c < 16; ++c) {
                float4 wq = ldx4<F32>(W3, t * 16384 + h * 256 + c * 16 + o4 * 4);
                float g0v = sm.u.g.G[0][c][h];
                acc[0][0] += g0v * wq.x; acc[0][1] += g0v * wq.y;
                acc[0][2] += g0v * wq.z; acc[0][3] += g0v * wq.w;
                if (dt == 3) {
                    float g1v = sm.u.g.G[1][c][h];
                    float g2v = sm.u.g.G[2][c][h];
                    acc[1][0] += g1v * wq.x; acc[1][1] += g1v * wq.y;
                    acc[1][2] += g1v * wq.z; acc[1][3] += g1v * wq.w;
                    acc[2][0] += g2v * wq.x; acc[2][1] += g2v * wq.y;
                    acc[2][2] += g2v * wq.z; acc[2][3] += g2v * wq.w;
                }
            }
            // reduce over h bits 0,1 only (lane bits 2,3): each lane then
            // holds the sum over its h-quad for its o4
#pragma unroll
            for (int m = 4; m <= 8; m <<= 1) {
#pragma unroll
                for (int d = 0; d < 3; ++d) {
                    if (d < dt) {
#pragma unroll
                        for (int oo = 0; oo < 4; ++oo)
                            acc[d][oo] += __shfl_xor(acc[d][oo], m);
                    }
                }
            }
            if ((lane & 12) == 0) {            // h%4==0 representatives (16/wave)
                const int hql = lane >> 4;     // h-quad within wave (h bits 2,3)
                const int o4r = lane & 3;
#pragma unroll
                for (int d = 0; d < 3; ++d) {
                    if (d < dt) {
#pragma unroll
                        for (int oo = 0; oo < 4; ++oo)
                            sm.v.red2[wv][hql][o4r * 4 + oo][d] = acc[d][oo];
                    }
                }
            }
        }
        __syncthreads();

        // ---- phase F: combine 16 partials (4 waves x 4 h-quads) + b3*S ----
        if (tid < 16 * dt) {
            int o = tid & 15, d = tid >> 4;
            float s = 0.f;
#pragma unroll
            for (int w = 0; w < 4; ++w)
#pragma unroll
                for (int q = 0; q < 4; ++q)
                    s += sm.v.red2[w][q][o][d];
#pragma unroll 4
            for (int c = 0; c < 16; ++c)
                s += ldf<F32>(b3, t * 256 + c * 16 + o) * sm.S[d][c];
            if (ot_arr[t] == 0) sm.out0[o] += s;
            else                sm.out1[o][d] += s;
        }
        __syncthreads();
    }

    // ---- epilogue (proven) ----
    if (tid < 32) {
        if (tid < 16) {
            int c = tid;
            float v = sm.out0[c];
            float nrm = fmaxf(fabsf(v), 1e-8f);
            float mu = nrm;
#pragma unroll
            for (int m = 8; m >= 1; m >>= 1) mu += __shfl_xor(mu, m, 16);
            mu *= (1.0f / 16.0f);
            float dl = nrm - mu;
            float var = dl * dl;
#pragma unroll
            for (int m = 8; m >= 1; m >>= 1) var += __shfl_xor(var, m, 16);
            var *= (1.0f / 16.0f);
            float scaled = dl / sqrtf(var + 1e-5f) * ldf<F32>(lg0, c) + ldf<F32>(lb0, c);
            sm.f0g[c] = v / nrm * scaled;
        } else {
            int c = tid - 16;
            float x = sm.out1[c][0], y = sm.out1[c][1], z = sm.out1[c][2];
            float nrm = fmaxf(sqrtf(x * x + y * y + z * z), 1e-8f);
            float mu = nrm;
#pragma unroll
            for (int m = 8; m >= 1; m >>= 1) mu += __shfl_xor(mu, m, 16);
            mu *= (1.0f / 16.0f);
            float dl = nrm - mu;
            float var = dl * dl;
#pragma unroll
            for (int m = 8; m >= 1; m >>= 1) var += __shfl_xor(var, m, 16);
            var *= (1.0f / 16.0f);
            float scaled = dl / sqrtf(var + 1e-5f) * ldf<F32>(lg1, c) + ldf<F32>(lb1, c);
            sm.fac1[c] = scaled / nrm;
        }
    }
    __syncthreads();
    if (tid < 16) {
        int o = tid;
        float a0 = ldf<F32>(gb0, o), a1 = ldf<F32>(gb1, o);
        float r0 = 0, rx = 0, ry = 0, rz = 0;
#pragma unroll 4
        for (int c = 0; c < 16; ++c) {
            float fg = sm.f0g[c];
            a0 += fg * ldf<F32>(gW0, c * 16 + o);
            a1 += fg * ldf<F32>(gW1, c * 16 + o);
            r0 += sm.f0self[c] * ldf<F32>(rW0, c * 16 + o);
            float rw1 = ldf<F32>(rW1, c * 16 + o);
            rx += sm.f1self[c][0] * rw1; ry += sm.f1self[c][1] * rw1; rz += sm.f1self[c][2] * rw1;
        }
        float g0v = 1.f / (1.f + __expf(-a0));
        float g1v = 1.f / (1.f + __expf(-a1));
        stf<F32>(out, n * 16 + o, sm.f0g[o] * g0v + r0);
        int b = NNODES * CC + (n * 16 + o) * 3;
        float fac = sm.fac1[o] * g1v;
        stf<F32>(out, b + 0, sm.out1[o][0] * fac + rx);
        stf<F32>(out, b + 1, sm.out1[o][1] * fac + ry);
        stf<F32>(out, b + 2, sm.out1[o][2] * fac + rz);
    }
}

__global__ __launch_bounds__(256)
void gttfn_kernel(const void* f0,  const void* f1,
                  const void* rbf, const void* gte,
                  const void* W1,  const void* b1,
                  const void* W2,  const void* b2,
                  const void* W3,  const void* b3,
                  const void* lg0, const void* lb0,
                  const void* lg1, const void* lb1,
                  const void* gW0, const void* gb0,
                  const void* gW1, const void* gb1,
                  const void* rW0, const void* rW1,
                  const void* nbr_v,
                  void* out)
{
    __shared__ Smem sm;
    __shared__ int flags[2];
    const int tid = threadIdx.x;

    if (tid < 64) {
        const u16* u = (const u16*)f0;
        unsigned short w = u[2 * tid];
        int e = (w >> 7) & 0xFF;
        bool garbage = (e >= 0x83) || (e <= 0x30);
        bool isF32 = __any(garbage);
        const int* ni = (const int*)nbr_v;
        bool hi_nonzero = (tid < 32) ? (ni[2 * tid + 1] != 0) : false;
        bool isI64 = !__any(hi_nonzero);
        if (tid == 0) { flags[0] = isF32 ? 1 : 0; flags[1] = isI64 ? 1 : 0; }
    }
    __syncthreads();
    int fF32 = flags[0], fI64 = flags[1];

    const int* nbr = (const int*)nbr_v;
    if (fF32) {
        if (fI64) gttfn_body<true, true >(sm, f0,f1,rbf,gte,W1,b1,W2,b2,W3,b3,lg0,lb0,lg1,lb1,gW0,gb0,gW1,gb1,rW0,rW1,nbr,out);
        else      gttfn_body<true, false>(sm, f0,f1,rbf,gte,W1,b1,W2,b2,W3,b3,lg0,lb0,lg1,lb1,gW0,gb0,gW1,gb1,rW0,rW1,nbr,out);
    } else {
        if (fI64) gttfn_body<false, true >(sm, f0,f1,rbf,gte,W1,b1,W2,b2,W3,b3,lg0,lb0,lg1,lb1,gW0,gb0,gW1,gb1,rW0,rW1,nbr,out);
        else      gttfn_body<false, false>(sm, f0,f1,rbf,gte,W1,b1,W2,b2,W3,b3,lg0,lb0,lg1,lb1,gW0,gb0,gW1,gb1,rW0,rW1,nbr,out);
    }
}

extern "C" void kernel_launch(void* const* d_in, const int* in_sizes, int n_in,
                              void* d_out, int out_size, void* d_ws, size_t ws_size,
                              hipStream_t stream) {
    gttfn_kernel<<<dim3(NNODES), dim3(256), 0, stream>>>(
        d_in[0],  d_in[1],  d_in[2],  d_in[3],
        d_in[4],  d_in[5],  d_in[6],  d_in[7],
        d_in[8],  d_in[9],  d_in[10], d_in[11],
        d_in[12], d_in[13], d_in[14], d_in[15],
        d_in[16], d_in[17], d_in[18], d_in[19],
        d_in[20], d_out);
}

// Round 11
// 680.033 us; speedup vs baseline: 1.1930x; 1.0052x over previous
//
#include <hip/hip_runtime.h>

#define NNODES 8192
#define KN 32
#define CC 16
#define HD 64

typedef unsigned short u16;

__device__ __forceinline__ float bf2f(u16 u) {
    union { unsigned int i; float f; } v; v.i = ((unsigned int)u) << 16; return v.f;
}
__device__ __forceinline__ u16 f2bf(float f) {
    union { float ff; unsigned int i; } v; v.ff = f;
    unsigned int r = v.i + 0x7FFFu + ((v.i >> 16) & 1u);
    return (u16)(r >> 16);
}
__device__ __forceinline__ float4 bf2f4(ushort4 u) {
    float4 r; r.x = bf2f(u.x); r.y = bf2f(u.y); r.z = bf2f(u.z); r.w = bf2f(u.w); return r;
}
__device__ __forceinline__ float silu_f(float x) { return x / (1.0f + __expf(-x)); }

template<bool F32>
__device__ __forceinline__ float ldf(const void* p, int i) {
    if constexpr (F32) return ((const float*)p)[i];
    else               return bf2f(((const u16*)p)[i]);
}
template<bool F32>
__device__ __forceinline__ float4 ldx4(const void* p, int i) {  // elements i..i+3, i%4==0
    if constexpr (F32) return ((const float4*)p)[i >> 2];
    else               return bf2f4(((const ushort4*)p)[i >> 2]);
}
template<bool F32>
__device__ __forceinline__ void stf(void* p, int i, float v) {
    if constexpr (F32) ((float*)p)[i] = v;
    else               ((u16*)p)[i] = f2bf(v);
}

__device__ __forceinline__ void fma4(float4& a, const float4 rv,
                                     const float4 w0, const float4 w1,
                                     const float4 w2, const float4 w3) {
    a.x += rv.x*w0.x + rv.y*w1.x + rv.z*w2.x + rv.w*w3.x;
    a.y += rv.x*w0.y + rv.y*w1.y + rv.z*w2.y + rv.w*w3.y;
    a.z += rv.x*w0.z + rv.y*w1.z + rv.z*w2.z + rv.w*w3.z;
    a.w += rv.x*w0.w + rv.y*w1.w + rv.z*w2.w + rv.w*w3.w;
}

// 53760 B -> 3 blocks/CU, identical footprint to r10 (683us best).
// LDS pipe ~98% busy is THE wall; every change removes LDS instructions
// while keeping all 256 threads issuing (r9 lesson).
// red2 overlays con: con live A->D, red2 live E->F, barrier-separated.
struct __align__(16) Smem {
    union {
        float W2s[HD * HD];                      // 16384 B, live stage->C
        struct { float G[3][16][68]; } g;        // 13056 B, live D->E
    } u;
    union {
        float con[KN][CC][4];                    // 8192 B, live A->D
        float red2[4][4][16][3];                 // 3072 B, live E->F [wave][hql][o][d]
    } v;
    float rbf[KN][16];       // 2048
    float e[KN][4];          // 512
    float f0n[KN][CC];       // 2048
    float f1n[KN][CC][3];    // 6144
    float h1[KN][68];        // 8704  (row padded 64->68)
    float h2[KN][68];        // 8704
    float S[3][CC];          // 192
    float out0[CC];
    float out1[CC][3];
    float f0self[CC];
    float f1self[CC][3];
    float f0g[CC];
    float fac1[CC];
};

template<bool F32, bool I64>
__device__ void gttfn_body(Smem& sm,
                           const void* f0,  const void* f1,
                           const void* rbf, const void* gte,
                           const void* W1,  const void* b1,
                           const void* W2,  const void* b2,
                           const void* W3,  const void* b3,
                           const void* lg0, const void* lb0,
                           const void* lg1, const void* lb1,
                           const void* gW0, const void* gb0,
                           const void* gW1, const void* gb1,
                           const void* rW0, const void* rW1,
                           const int* __restrict__ nbr,
                           void* out)
{
    const int tid  = threadIdx.x;
    const int n    = blockIdx.x;
    const int lane = tid & 63;
    const int wv   = tid >> 6;

    // ---- preamble (proven) ----
    for (int i = tid; i < KN * 16; i += 256)
        ((float*)sm.rbf)[i] = ldf<F32>(rbf, n * KN * 16 + i);
    if (tid < KN * 4)
        ((float*)sm.e)[tid] = ldf<F32>(gte, n * KN * 4 + tid);
    for (int idx = tid; idx < KN * CC; idx += 256) {
        int j = idx >> 4, c = idx & 15;
        int nb = I64 ? nbr[2 * (n * KN + j)] : nbr[n * KN + j];
        sm.f0n[j][c] = ldf<F32>(f0, nb * CC + c);
        int base = (nb * CC + c) * 3;
        sm.f1n[j][c][0] = ldf<F32>(f1, base + 0);
        sm.f1n[j][c][1] = ldf<F32>(f1, base + 1);
        sm.f1n[j][c][2] = ldf<F32>(f1, base + 2);
    }
    if (tid < CC) { sm.f0self[tid] = ldf<F32>(f0, n * CC + tid); sm.out0[tid] = 0.f; }
    else if (tid < CC + 48) {
        int k = tid - CC;
        ((float*)sm.f1self)[k] = ldf<F32>(f1, n * CC * 3 + k);
        ((float*)sm.out1)[k] = 0.f;
    }
    __syncthreads();

    const int dot_arr[5] = {1, 3, 3, 1, 3};
    const int ot_arr[5]  = {0, 1, 1, 0, 1};

    for (int t = 0; t < 5; ++t) {
        const int dt = dot_arr[t];

        // ---- phase A: con fp32, float4 e-read + ONE float4 con-write ----
        for (int idx = tid; idx < KN * CC; idx += 256) {
            int j = idx >> 4, c = idx & 15;
            float4 ev = *(const float4*)&sm.e[j][0];   // e0, ex, ey, ez
            float4 cv; cv.y = 0.f; cv.z = 0.f; cv.w = 0.f;
            if (t == 0) {
                cv.x = ev.x * sm.f0n[j][c];
            } else if (t == 1) {
                float fv = sm.f0n[j][c];
                cv.x = ev.y * fv; cv.y = ev.z * fv; cv.z = ev.w * fv;
            } else if (t == 2) {
                cv.x = ev.x * sm.f1n[j][c][0];
                cv.y = ev.x * sm.f1n[j][c][1];
                cv.z = ev.x * sm.f1n[j][c][2];
            } else if (t == 3) {
                cv.x = ev.y * sm.f1n[j][c][0] + ev.z * sm.f1n[j][c][1]
                     + ev.w * sm.f1n[j][c][2];
            } else {
                float fx = sm.f1n[j][c][0], fy = sm.f1n[j][c][1], fz = sm.f1n[j][c][2];
                cv.x = fy * ev.w - fz * ev.z;
                cv.y = fz * ev.y - fx * ev.w;
                cv.z = fx * ev.z - fy * ev.y;
            }
            *(float4*)&sm.v.con[j][c][0] = cv;
        }

        // ---- stage W2[t] -> LDS fp32 (32x reuse in phase C) ----
        for (int i = tid; i < 1024; i += 256) {
            float4 w = ldx4<F32>(W2, t * 4096 + i * 4);
            *(float4*)&sm.u.W2s[i * 4] = w;
        }

        // ---- phase B: h1 = silu(rbf @ W1 + b1), fp32 (proven) ----
        for (int task = tid; task < KN * 16; task += 256) {
            int j = task >> 4, hq = task & 15;
            float4 acc = ldx4<F32>(b1, t * 64 + hq * 4);
            const float4* rrow = (const float4*)(&sm.rbf[j][0]);
#pragma unroll
            for (int r4 = 0; r4 < 4; ++r4) {
                float4 rv = rrow[r4];
                float4 w0 = ldx4<F32>(W1, t * 1024 + (r4 * 4 + 0) * 64 + hq * 4);
                float4 w1 = ldx4<F32>(W1, t * 1024 + (r4 * 4 + 1) * 64 + hq * 4);
                float4 w2 = ldx4<F32>(W1, t * 1024 + (r4 * 4 + 2) * 64 + hq * 4);
                float4 w3 = ldx4<F32>(W1, t * 1024 + (r4 * 4 + 3) * 64 + hq * 4);
                acc.x += rv.x * w0.x + rv.y * w1.x + rv.z * w2.x + rv.w * w3.x;
                acc.y += rv.x * w0.y + rv.y * w1.y + rv.z * w2.y + rv.w * w3.y;
                acc.z += rv.x * w0.z + rv.y * w1.z + rv.z * w2.z + rv.w * w3.z;
                acc.w += rv.x * w0.w + rv.y * w1.w + rv.z * w2.w + rv.w * w3.w;
            }
            float4 r;
            r.x = silu_f(acc.x); r.y = silu_f(acc.y);
            r.z = silu_f(acc.z); r.w = silu_f(acc.w);
            *(float4*)&sm.h1[j][hq * 4] = r;
        }
        __syncthreads();

        // ---- phase C: h2 = silu(h1 @ W2s + b2) -- lane-pair h-split:
        // pair (l, l^32) owns a 4j x 4o tile; each lane does half the h
        // range; combine via 8 shfl_xor(32) (exchange-select). LDS reads
        // 96 -> 64 per thread; all 256 threads active. ----
        {
            const int l31 = lane & 31;
            const int tile = wv * 32 + l31;       // 0..127 (bijective)
            const int jq = tile >> 4;             // 0..7
            const int hq = tile & 15;             // 0..15
            const int hh = lane >> 5;             // 0 | 1 (h-half)
            const int j0 = jq * 4;
            float4 b = ldx4<F32>(b2, t * 64 + hq * 4);   // issue early (vmem)
            float4 a0 = make_float4(0, 0, 0, 0), a1 = a0, a2 = a0, a3 = a0;
#pragma unroll 4
            for (int i8 = 0; i8 < 8; ++i8) {
                const int h4 = hh * 8 + i8;
                const float* Wr = &sm.u.W2s[(h4 * 4) * 64 + hq * 4];
                float4 w0 = *(const float4*)(Wr);
                float4 w1 = *(const float4*)(Wr + 64);
                float4 w2 = *(const float4*)(Wr + 128);
                float4 w3 = *(const float4*)(Wr + 192);
                float4 hv0 = *(const float4*)&sm.h1[j0 + 0][h4 * 4];
                float4 hv1 = *(const float4*)&sm.h1[j0 + 1][h4 * 4];
                float4 hv2 = *(const float4*)&sm.h1[j0 + 2][h4 * 4];
                float4 hv3 = *(const float4*)&sm.h1[j0 + 3][h4 * 4];
                fma4(a0, hv0, w0, w1, w2, w3);
                fma4(a1, hv1, w0, w1, w2, w3);
                fma4(a2, hv2, w0, w1, w2, w3);
                fma4(a3, hv3, w0, w1, w2, w3);
            }
            // exchange-select: ship partner's rows, receive mine (8 shuffles)
            const bool lo = (hh == 0);
            float4 eA, eB;                       // what I give = partner's rows
            eA.x = lo ? a2.x : a0.x; eA.y = lo ? a2.y : a0.y;
            eA.z = lo ? a2.z : a0.z; eA.w = lo ? a2.w : a0.w;
            eB.x = lo ? a3.x : a1.x; eB.y = lo ? a3.y : a1.y;
            eB.z = lo ? a3.z : a1.z; eB.w = lo ? a3.w : a1.w;
            eA.x = __shfl_xor(eA.x, 32); eA.y = __shfl_xor(eA.y, 32);
            eA.z = __shfl_xor(eA.z, 32); eA.w = __shfl_xor(eA.w, 32);
            eB.x = __shfl_xor(eB.x, 32); eB.y = __shfl_xor(eB.y, 32);
            eB.z = __shfl_xor(eB.z, 32); eB.w = __shfl_xor(eB.w, 32);
            float4 mA, mB;                       // my partial for my rows
            mA.x = lo ? a0.x : a2.x; mA.y = lo ? a0.y : a2.y;
            mA.z = lo ? a0.z : a2.z; mA.w = lo ? a0.w : a2.w;
            mB.x = lo ? a1.x : a3.x; mB.y = lo ? a1.y : a3.y;
            mB.z = lo ? a1.z : a3.z; mB.w = lo ? a1.w : a3.w;
            mA.x += eA.x + b.x; mA.y += eA.y + b.y;
            mA.z += eA.z + b.z; mA.w += eA.w + b.w;
            mB.x += eB.x + b.x; mB.y += eB.y + b.y;
            mB.z += eB.z + b.z; mB.w += eB.w + b.w;
            float4 r0, r1;
            r0.x = silu_f(mA.x); r0.y = silu_f(mA.y);
            r0.z = silu_f(mA.z); r0.w = silu_f(mA.w);
            r1.x = silu_f(mB.x); r1.y = silu_f(mB.y);
            r1.z = silu_f(mB.z); r1.w = silu_f(mB.w);
            const int jw = j0 + hh * 2;          // hh0: j0,j0+1; hh1: j0+2,j0+3
            *(float4*)&sm.h2[jw][hq * 4]     = r0;
            *(float4*)&sm.h2[jw + 1][hq * 4] = r1;
        }
        __syncthreads();

        // ---- phase D: G[d][c][h] + S, branch-free hot loop (proven, 256 thr) ----
        {
            int hq = tid & 15, c = tid >> 4;
            float4 g0 = make_float4(0, 0, 0, 0), g1 = g0, g2 = g0;
            float sx = 0, sy = 0, sz = 0;
            if (dt == 1) {
#pragma unroll 4
                for (int j = 0; j < KN; ++j) {
                    float4 h2q = *(const float4*)&sm.h2[j][hq * 4];
                    float cv = sm.v.con[j][c][0];
                    g0.x += h2q.x * cv; g0.y += h2q.y * cv;
                    g0.z += h2q.z * cv; g0.w += h2q.w * cv;
                    sx += cv;
                }
            } else {
#pragma unroll 4
                for (int j = 0; j < KN; ++j) {
                    float4 h2q = *(const float4*)&sm.h2[j][hq * 4];
                    float4 cv = *(const float4*)&sm.v.con[j][c][0];
                    g0.x += h2q.x * cv.x; g0.y += h2q.y * cv.x; g0.z += h2q.z * cv.x; g0.w += h2q.w * cv.x;
                    g1.x += h2q.x * cv.y; g1.y += h2q.y * cv.y; g1.z += h2q.z * cv.y; g1.w += h2q.w * cv.y;
                    g2.x += h2q.x * cv.z; g2.y += h2q.y * cv.z; g2.z += h2q.z * cv.z; g2.w += h2q.w * cv.z;
                    sx += cv.x; sy += cv.y; sz += cv.z;
                }
            }
            *(float4*)&sm.u.g.G[0][c][hq * 4] = g0;
            if (dt == 3) {
                *(float4*)&sm.u.g.G[1][c][hq * 4] = g1;
                *(float4*)&sm.u.g.G[2][c][hq * 4] = g2;
            }
            if (hq == 0) {
                sm.S[0][c] = sx;
                if (dt == 3) { sm.S[1][c] = sy; sm.S[2][c] = sz; }
            }
        }
        __syncthreads();

        // ---- phase E: G @ W3; 2-step shuffle (h-quad sums) -> red2 (r10-proven) ----
        {
            const int h = tid >> 2, o4 = tid & 3;
            float acc[3][4] = {{0,0,0,0},{0,0,0,0},{0,0,0,0}};
#pragma unroll 4
            for (int c = 0; c < 16; ++c) {
                float4 wq = ldx4<F32>(W3, t * 16384 + h * 256 + c * 16 + o4 * 4);
                float g0v = sm.u.g.G[0][c][h];
                acc[0][0] += g0v * wq.x; acc[0][1] += g0v * wq.y;
                acc[0][2] += g0v * wq.z; acc[0][3] += g0v * wq.w;
                if (dt == 3) {
                    float g1v = sm.u.g.G[1][c][h];
                    float g2v = sm.u.g.G[2][c][h];
                    acc[1][0] += g1v * wq.x; acc[1][1] += g1v * wq.y;
                    acc[1][2] += g1v * wq.z; acc[1][3] += g1v * wq.w;
                    acc[2][0] += g2v * wq.x; acc[2][1] += g2v * wq.y;
                    acc[2][2] += g2v * wq.z; acc[2][3] += g2v * wq.w;
                }
            }
#pragma unroll
            for (int m = 4; m <= 8; m <<= 1) {
#pragma unroll
                for (int d = 0; d < 3; ++d) {
                    if (d < dt) {
#pragma unroll
                        for (int oo = 0; oo < 4; ++oo)
                            acc[d][oo] += __shfl_xor(acc[d][oo], m);
                    }
                }
            }
            if ((lane & 12) == 0) {            // h%4==0 representatives (16/wave)
                const int hql = lane >> 4;     // h-quad within wave (h bits 2,3)
                const int o4r = lane & 3;
#pragma unroll
                for (int d = 0; d < 3; ++d) {
                    if (d < dt) {
#pragma unroll
                        for (int oo = 0; oo < 4; ++oo)
                            sm.v.red2[wv][hql][o4r * 4 + oo][d] = acc[d][oo];
                    }
                }
            }
        }
        __syncthreads();

        // ---- phase F: combine 16 partials (4 waves x 4 h-quads) + b3*S ----
        if (tid < 16 * dt) {
            int o = tid & 15, d = tid >> 4;
            float s = 0.f;
#pragma unroll
            for (int w = 0; w < 4; ++w)
#pragma unroll
                for (int q = 0; q < 4; ++q)
                    s += sm.v.red2[w][q][o][d];
#pragma unroll 4
            for (int c = 0; c < 16; ++c)
                s += ldf<F32>(b3, t * 256 + c * 16 + o) * sm.S[d][c];
            if (ot_arr[t] == 0) sm.out0[o] += s;
            else                sm.out1[o][d] += s;
        }
        __syncthreads();
    }

    // ---- epilogue (proven) ----
    if (tid < 32) {
        if (tid < 16) {
            int c = tid;
            float v = sm.out0[c];
            float nrm = fmaxf(fabsf(v), 1e-8f);
            float mu = nrm;
#pragma unroll
            for (int m = 8; m >= 1; m >>= 1) mu += __shfl_xor(mu, m, 16);
            mu *= (1.0f / 16.0f);
            float dl = nrm - mu;
            float var = dl * dl;
#pragma unroll
            for (int m = 8; m >= 1; m >>= 1) var += __shfl_xor(var, m, 16);
            var *= (1.0f / 16.0f);
            float scaled = dl / sqrtf(var + 1e-5f) * ldf<F32>(lg0, c) + ldf<F32>(lb0, c);
            sm.f0g[c] = v / nrm * scaled;
        } else {
            int c = tid - 16;
            float x = sm.out1[c][0], y = sm.out1[c][1], z = sm.out1[c][2];
            float nrm = fmaxf(sqrtf(x * x + y * y + z * z), 1e-8f);
            float mu = nrm;
#pragma unroll
            for (int m = 8; m >= 1; m >>= 1) mu += __shfl_xor(mu, m, 16);
            mu *= (1.0f / 16.0f);
            float dl = nrm - mu;
            float var = dl * dl;
#pragma unroll
            for (int m = 8; m >= 1; m >>= 1) var += __shfl_xor(var, m, 16);
            var *= (1.0f / 16.0f);
            float scaled = dl / sqrtf(var + 1e-5f) * ldf<F32>(lg1, c) + ldf<F32>(lb1, c);
            sm.fac1[c] = scaled / nrm;
        }
    }
    __syncthreads();
    if (tid < 16) {
        int o = tid;
        float a0 = ldf<F32>(gb0, o), a1 = ldf<F32>(gb1, o);
        float r0 = 0, rx = 0, ry = 0, rz = 0;
#pragma unroll 4
        for (int c = 0; c < 16; ++c) {
            float fg = sm.f0g[c];
            a0 += fg * ldf<F32>(gW0, c * 16 + o);
            a1 += fg * ldf<F32>(gW1, c * 16 + o);
            r0 += sm.f0self[c] * ldf<F32>(rW0, c * 16 + o);
            float rw1 = ldf<F32>(rW1, c * 16 + o);
            rx += sm.f1self[c][0] * rw1; ry += sm.f1self[c][1] * rw1; rz += sm.f1self[c][2] * rw1;
        }
        float g0v = 1.f / (1.f + __expf(-a0));
        float g1v = 1.f / (1.f + __expf(-a1));
        stf<F32>(out, n * 16 + o, sm.f0g[o] * g0v + r0);
        int b = NNODES * CC + (n * 16 + o) * 3;
        float fac = sm.fac1[o] * g1v;
        stf<F32>(out, b + 0, sm.out1[o][0] * fac + rx);
        stf<F32>(out, b + 1, sm.out1[o][1] * fac + ry);
        stf<F32>(out, b + 2, sm.out1[o][2] * fac + rz);
    }
}

__global__ __launch_bounds__(256)
void gttfn_kernel(const void* f0,  const void* f1,
                  const void* rbf, const void* gte,
                  const void* W1,  const void* b1,
                  const void* W2,  const void* b2,
                  const void* W3,  const void* b3,
                  const void* lg0, const void* lb0,
                  const void* lg1, const void* lb1,
                  const void* gW0, const void* gb0,
                  const void* gW1, const void* gb1,
                  const void* rW0, const void* rW1,
                  const void* nbr_v,
                  void* out)
{
    __shared__ Smem sm;
    __shared__ int flags[2];
    const int tid = threadIdx.x;

    if (tid < 64) {
        const u16* u = (const u16*)f0;
        unsigned short w = u[2 * tid];
        int e = (w >> 7) & 0xFF;
        bool garbage = (e >= 0x83) || (e <= 0x30);
        bool isF32 = __any(garbage);
        const int* ni = (const int*)nbr_v;
        bool hi_nonzero = (tid < 32) ? (ni[2 * tid + 1] != 0) : false;
        bool isI64 = !__any(hi_nonzero);
        if (tid == 0) { flags[0] = isF32 ? 1 : 0; flags[1] = isI64 ? 1 : 0; }
    }
    __syncthreads();
    int fF32 = flags[0], fI64 = flags[1];

    const int* nbr = (const int*)nbr_v;
    if (fF32) {
        if (fI64) gttfn_body<true, true >(sm, f0,f1,rbf,gte,W1,b1,W2,b2,W3,b3,lg0,lb0,lg1,lb1,gW0,gb0,gW1,gb1,rW0,rW1,nbr,out);
        else      gttfn_body<true, false>(sm, f0,f1,rbf,gte,W1,b1,W2,b2,W3,b3,lg0,lb0,lg1,lb1,gW0,gb0,gW1,gb1,rW0,rW1,nbr,out);
    } else {
        if (fI64) gttfn_body<false, true >(sm, f0,f1,rbf,gte,W1,b1,W2,b2,W3,b3,lg0,lb0,lg1,lb1,gW0,gb0,gW1,gb1,rW0,rW1,nbr,out);
        else      gttfn_body<false, false>(sm, f0,f1,rbf,gte,W1,b1,W2,b2,W3,b3,lg0,lb0,lg1,lb1,gW0,gb0,gW1,gb1,rW0,rW1,nbr,out);
    }
}

extern "C" void kernel_launch(void* const* d_in, const int* in_sizes, int n_in,
                              void* d_out, int out_size, void* d_ws, size_t ws_size,
                              hipStream_t stream) {
    gttfn_kernel<<<dim3(NNODES), dim3(256), 0, stream>>>(
        d_in[0],  d_in[1],  d_in[2],  d_in[3],
        d_in[4],  d_in[5],  d_in[6],  d_in[7],
        d_in[8],  d_in[9],  d_in[10], d_in[11],
        d_in[12], d_in[13], d_in[14], d_in[15],
        d_in[16], d_in[17], d_in[18], d_in[19],
        d_in[20], d_out);
}